// Round 8
// baseline (319.658 us; speedup 1.0000x reference)
//
#include <hip/hip_runtime.h>
#include <hip/hip_bf16.h>
#include <cstdint>
#include <cstddef>

// ---------------------------------------------------------------------------
// LRU layer (fp32 I/O): h = scan( (x W_in^T + b_in)*gamma, lambda, mask )
//                       out = LN( Re(h W_out^T + b_out) + x )
// B=8 L=2048 D=512 H=1024.
// ROUND-17: scan-fold kept, but the in-LDS scan is REGISTER-BATCHED.
// Round-15/16's element-at-a-time in-place rewrite serialized as
// ds_read->wait->VALU->ds_write per row (compiler must assume aliasing
// through the cast pointer): ~6.7k cyc/step on the critical path => +89us.
// The scan's LDS addresses are static; only the FMA chain is dependent.
// Now: batch-load 32 rows (+mask factors) into regs, run the 32-step
// recurrence in registers (~400 cyc), batch-store.  ~700 cyc/step, which
// fits in the ~3.4k cyc/step of staging slack measured in round 4
// (63us = 4.7k cyc/step budget vs ~1.3k compute) => scan rides free.
// Math unchanged: scan_full's exact expressions, one f2b per element.
// GEMM structure = round-4-verified: cooperative gl2lds double-buffer,
// counted vmcnt(9), raw s_barrier.  Wave0 prefetches lambda+carry (t+1)
// during step t; in-order retirement keeps the vmcnt ledger exact.
// Pipeline: prep_all -> gemm_scan -> scan_carry -> gemm2_ln.
// ---------------------------------------------------------------------------

typedef unsigned short u16;
typedef __attribute__((ext_vector_type(8))) short bf16x8;   // 8 bf16 = 4 VGPRs
typedef __attribute__((ext_vector_type(4))) float f32x4;

#define B_    8
#define L_    2048
#define D_    512
#define H_    1024
#define M_    (B_ * L_)      // 16384 rows
#define SEG_  64             // scan segments per batch
#define T_    (L_ / SEG_)    // 32 steps/segment

__device__ __forceinline__ float b2f(u16 u) {
  union { unsigned int i; float f; } v; v.i = ((unsigned int)u) << 16; return v.f;
}
__device__ __forceinline__ u16 f2b(float f) {
  union { float f; unsigned int i; } v; v.f = f;
  unsigned int x = v.i;
  return (u16)((x + 0x7fffu + ((x >> 16) & 1u)) >> 16);   // RNE
}

// async global->LDS, 16B per lane. LDS dst must be wave-uniform base + lane*16.
__device__ __forceinline__ void gl2lds16(const void* g, void* l) {
  __builtin_amdgcn_global_load_lds(
      (const __attribute__((address_space(1))) void*)g,
      (__attribute__((address_space(3))) void*)l, 16, 0, 0);
}

// XOR swizzle of the 8 16B-chunks in a 64-wide K row (BK=64).
__device__ __forceinline__ int ksw8(int row, int c) {
  return (c ^ (row & 7)) & 7;
}

// ---------------------------------------------------------------------------
// prep_all: x fp32->bf16 + interleaved weight prep + lamtab:
//   winb[2c][k]   = bf16(W_in_re[c][k] * gamma_c)
//   winb[2c+1][k] = bf16(W_in_im[c][k] * gamma_c)
//   wcat[d][2c]   = bf16(W_out_re[d][c]);  wcat[d][2c+1] = bf16(-W_out_im[d][c])
//   bb[2c] = b_in_re[c]*gamma_c;  bb[2c+1] = b_in_im[c]*gamma_c
//   lamtab[c] = (Re lambda_c, Im lambda_c)
// ---------------------------------------------------------------------------
__global__ __launch_bounds__(256) void prep_all(
    const float* __restrict__ x, u16* __restrict__ xb,
    const float* __restrict__ wire, const float* __restrict__ wiim,
    const float* __restrict__ wore, const float* __restrict__ woim,
    const float* __restrict__ bire, const float* __restrict__ biim,
    const float* __restrict__ params,
    u16* __restrict__ winb, u16* __restrict__ wcat, float* __restrict__ bb,
    float2* __restrict__ lamtab)
{
  int i = blockIdx.x * 256 + threadIdx.x;        // 0 .. 524287
#pragma unroll
  for (int j = 0; j < 4; ++j) {                  // x: 2097152 float4 groups
    int gi = i + j * 524288;
    float4 v = ((const float4*)x)[gi];
    ushort4 o;
    o.x = f2b(v.x); o.y = f2b(v.y); o.z = f2b(v.z); o.w = f2b(v.w);
    ((ushort4*)xb)[gi] = o;
  }
  {
    int cp = i >> 9, k = i & 511;                // W_in: (pair, k)
    float g = expf(params[2 * H_ + cp]);
    winb[(size_t)(2 * cp) * 512 + k]     = f2b(wire[i] * g);
    winb[(size_t)(2 * cp + 1) * 512 + k] = f2b(wiim[i] * g);
  }
  {
    int d = i >> 10, c = i & 1023;               // W_out: (d, c)
    wcat[(size_t)d * 2048 + 2 * c]     = f2b(wore[i]);
    wcat[(size_t)d * 2048 + 2 * c + 1] = f2b(-woim[i]);
  }
  if (i < 1024) {
    float gb = expf(params[2 * H_ + i]);
    bb[2 * i]     = bire[i] * gb;
    bb[2 * i + 1] = biim[i] * gb;
    float nu = expf(params[i]);
    float th = expf(params[H_ + i]);
    float mg = expf(-nu);
    lamtab[i] = make_float2(mg * cosf(th), mg * sinf(th));
  }
}

// ---------------------------------------------------------------------------
// gemm_scan: xh = x @ winb^T + bb (pre-scan) AND segfin/prodm of the
// segment-local scan over the in-LDS tile.
// 128x128 tile, BK=64, LDS-DMA staging, operand-swapped MFMA.
// ---------------------------------------------------------------------------
__global__ __launch_bounds__(256, 4) void gemm_scan(
    const u16* __restrict__ A, const u16* __restrict__ Bp,
    const float* __restrict__ mask, const float* __restrict__ params,
    u16* __restrict__ h, const float* __restrict__ bb,
    float2* __restrict__ segfin, float* __restrict__ prodm)
{
  __shared__ __align__(16) u16 sAB[16384];   // 32 KB: sA=[0,8192) sB=[8192,..)
  __shared__ float mf[128];
  const int K = 512;

  const int tid  = threadIdx.x;
  const int lane = tid & 63;
  const int wave = tid >> 6;
  const int wm = wave >> 1, wn = wave & 1;
  const int m0 = blockIdx.x * 128;           // m fast axis (XCD A-share)
  const int n0 = blockIdx.y * 128;
  const int b  = m0 >> 11;
  const int local0 = m0 & (L_ - 1);          // row offset within batch

  f32x4 acc[4][4];
#pragma unroll
  for (int i = 0; i < 4; ++i)
#pragma unroll
    for (int j = 0; j < 4; ++j) { f32x4 z = {0.f, 0.f, 0.f, 0.f}; acc[i][j] = z; }

  const int q = lane >> 4;
  const int r = lane & 15;

  for (int k0 = 0; k0 < K; k0 += 64) {
#pragma unroll
    for (int it = 0; it < 4; ++it) {
      int ci  = it * 256 + tid;
      int row = ci >> 3;
      int kc  = ksw8(row, ci & 7);
      gl2lds16(A  + (size_t)(m0 + row) * K + k0 + kc * 8, &sAB[ci * 8]);
      gl2lds16(Bp + (size_t)(n0 + row) * K + k0 + kc * 8, &sAB[8192 + ci * 8]);
    }
    __syncthreads();
#pragma unroll
    for (int kk = 0; kk < 2; ++kk) {
      const int cs = kk * 4 + q;
      bf16x8 af[4], bfv[4];
#pragma unroll
      for (int mt = 0; mt < 4; ++mt) {
        int arow = wm * 64 + mt * 16 + r;
        af[mt] = *(const bf16x8*)&sAB[(arow * 8 + ksw8(arow, cs)) * 8];
      }
#pragma unroll
      for (int nt = 0; nt < 4; ++nt) {
        int brow = wn * 64 + nt * 16 + r;
        bfv[nt] = *(const bf16x8*)&sAB[8192 + (brow * 8 + ksw8(brow, cs)) * 8];
      }
#pragma unroll
      for (int mt = 0; mt < 4; ++mt)
#pragma unroll
        for (int nt = 0; nt < 4; ++nt)
          acc[mt][nt] = __builtin_amdgcn_mfma_f32_16x16x32_bf16(
              bfv[nt], af[mt], acc[mt][nt], 0, 0, 0);
    }
    __syncthreads();
  }

  // ---- epilogue 1: bf16(acc+bias) -> sH[time 0..127][chan 0..127] ----
  u16* sH = sAB;                               // 128*128 u16 = 32 KB
  if (tid < 128)                               // stage mask factors
    mf[tid] = (local0 + tid == 0) ? 0.f
                                  : mask[b * L_ + local0 + tid - 1];
#pragma unroll
  for (int mt = 0; mt < 4; ++mt) {
    const int trow = wm * 64 + mt * 16 + r;    // time
    const int sw = (trow & 7) << 4;
#pragma unroll
    for (int nt = 0; nt < 4; ++nt) {
      const int nc = wn * 64 + nt * 16 + q * 4;  // channel (4 consecutive)
      const float4 b4 = *(const float4*)&bb[n0 + nc];
      ushort4 o;
      o.x = f2b(acc[mt][nt][0] + b4.x);
      o.y = f2b(acc[mt][nt][1] + b4.y);
      o.z = f2b(acc[mt][nt][2] + b4.z);
      o.w = f2b(acc[mt][nt][3] + b4.w);
      *(ushort4*)&sH[trow * 128 + (nc ^ sw)] = o;
    }
  }
  __syncthreads();

  // ---- epilogue 2: coalesced pre-scan store ----
#pragma unroll
  for (int it = 0; it < 8; ++it) {
    int flat = it * 256 + tid;                 // 0..2047 (16B chunks)
    int row  = flat >> 4;
    int c16  = (flat & 15) * 8;
    bf16x8 v = *(const bf16x8*)&sH[row * 128 + (c16 ^ ((row & 7) << 4))];
    *(bf16x8*)&h[(size_t)(m0 + row) * 2048 + n0 + c16] = v;
  }

  // ---- epilogue 3: per-wave segment scan -> segfin/prodm only ----
  {
    const int sIdx = wave;                     // 4 segments per block
    const int cpG  = (n0 >> 1) + lane;         // global complex pair
    float nu = expf(params[cpG]);
    float th = expf(params[H_ + cpG]);
    float mg = expf(-nu);
    float lr = mg * cosf(th), li = mg * sinf(th);
    float sr = 0.f, si = 0.f, pm = 1.f;
    const int rbase = sIdx * 32;
#pragma unroll
    for (int t = 0; t < 32; ++t) {
      int row = rbase + t;
      int pos = row * 128 + ((lane * 2) ^ ((row & 7) << 4));
      ushort2 v = *(const ushort2*)&sH[pos];
      float fac = mf[row];
      pm *= fac;
      float nr = b2f(v.x) + fac * (lr * sr - li * si);
      float ni = b2f(v.y) + fac * (lr * si + li * sr);
      sr = nr; si = ni;
    }
    const int sG = (local0 >> 5) + sIdx;       // global segment in batch
    segfin[(size_t)(b * SEG_ + sG) * H_ + cpG] = make_float2(sr, si);
    if (lane == 0 && n0 == 0) prodm[b * SEG_ + sG] = pm;
  }
}

// ---------------------------------------------------------------------------
// scan_carry: carries[s] = state entering segment s.
// ---------------------------------------------------------------------------
__global__ __launch_bounds__(256) void scan_carry(
    const float2* __restrict__ segfin, const float* __restrict__ prodm,
    const float* __restrict__ params, float2* __restrict__ carries)
{
  int idx = blockIdx.x * 256 + threadIdx.x;   // 0..8191
  int b = idx >> 10, cp = idx & 1023;
  float nu = expf(params[cp]);
  float th = expf(params[H_ + cp]);
  float mg = expf(-nu);
  float ltr = mg * cosf(th), lti = mg * sinf(th);
#pragma unroll
  for (int sq = 0; sq < 5; ++sq) {            // lambda^(2^5), T=32
    float nr = ltr * ltr - lti * lti;
    float ni = 2.f * ltr * lti;
    ltr = nr; lti = ni;
  }
  float cr = 0.f, ci = 0.f;
  float2 fin = segfin[(size_t)(b * SEG_) * H_ + cp];
  float pmv = prodm[b * SEG_];
  for (int s = 0; s < SEG_; ++s) {
    size_t o = (size_t)(b * SEG_ + s) * H_ + cp;
    carries[o] = make_float2(cr, ci);
    float2 finn; float pmn;
    if (s + 1 < SEG_) { finn = segfin[o + H_]; pmn = prodm[b * SEG_ + s + 1]; }
    float nr = fin.x + pmv * (ltr * cr - lti * ci);
    float ni = fin.y + pmv * (ltr * ci + lti * cr);
    cr = nr; ci = ni;
    fin = finn; pmv = pmn;
  }
}

// ---------------------------------------------------------------------------
// gemm2_ln: out = LN( scan(xh) @ wcat^T + b_out_re + x ),  scan fused.
// Tile 64(M) x 512(N), 512 threads = 8 waves (1m x 8n).  Cooperative gl2lds
// double-buffer + counted vmcnt(9) + raw s_barrier (round-4-verified).
// Per step, before fragment reads, wave 0 scans the staged A tile:
// BATCHED -- 32 ds_read_b32 (+mask factors) into regs, 32-step recurrence
// in registers, 32 ds_write_b32.  ~700 cyc on the critical path, absorbed
// by the ~3.4k cyc/step staging slack.  One f2b per element (bit-identical
// to scan_full).  lambda+carry for t+1 prefetched by wave0 during step t.
// ---------------------------------------------------------------------------
__global__ __launch_bounds__(512, 1) void gemm2_ln(
    const u16* __restrict__ A, const u16* __restrict__ Bp,
    const float* __restrict__ xg, const float* __restrict__ p0,
    const float* __restrict__ lnw, const float* __restrict__ lnb,
    const float* __restrict__ mask, const float2* __restrict__ lamtab,
    const float2* __restrict__ carries, float* __restrict__ out)
{
  __shared__ __align__(16) u16 smem[2][36864];    // 2 x 72 KB: A[0,4K) B[4K,36K)
  __shared__ float mf_s[64];
  __shared__ float red_s[512], red_ss[512];

  const int K = 2048;
  const int tid  = threadIdx.x;
  const int lane = tid & 63;
  const int wave = tid >> 6;                 // 0..7 == n-block
  const int m0 = blockIdx.x * 64;
  const int b  = m0 >> 11;
  const int local0 = m0 & (L_ - 1);
  const int s0 = local0 >> 5;                // first segment of this block
  const int q = lane >> 4;
  const int r = lane & 15;

  f32x4 acc[4][4];
#pragma unroll
  for (int i = 0; i < 4; ++i)
#pragma unroll
    for (int j = 0; j < 4; ++j) { f32x4 z = {0.f, 0.f, 0.f, 0.f}; acc[i][j] = z; }

  // stage one BK=64 K-tile: exactly 9 gl2lds per thread (A 1 + B 8).
  auto stage = [&](int bsel, int k0) {
    u16* sA = &smem[bsel][0];
    u16* sB = &smem[bsel][4096];
    {
      int ci  = tid;                         // 64 rows x 8 chunks
      int row = ci >> 3;
      int kc  = ksw8(row, ci & 7);
      gl2lds16(A + (size_t)(m0 + row) * K + k0 + kc * 8, sA + ci * 8);
    }
#pragma unroll
    for (int it = 0; it < 8; ++it) {         // 512 rows x 8 chunks
      int ci  = it * 512 + tid;
      int row = ci >> 3;
      int kc  = ksw8(row, ci & 7);
      gl2lds16(Bp + (size_t)row * K + k0 + kc * 8, sB + ci * 8);
    }
  };

  // scan lane mapping (wave 0): lane = (sp pair-in-tile, sg segment half)
  const int sp = lane & 31;
  const int sg = lane >> 5;
  const int schunk = sp >> 2;                // 16B chunk of this pair
  const int soff = (sp & 3) * 4;             // byte offset within chunk

  // lambda/carry prefetch (wave 0 only; 2 VMEM loads)
  float lrA = 0.f, liA = 0.f, crA = 0.f, ciA = 0.f;
  float lrB = 0.f, liB = 0.f, crB = 0.f, ciB = 0.f;

#define WAIT_VM9  asm volatile("s_waitcnt vmcnt(9)"  ::: "memory"); \
                  __builtin_amdgcn_sched_barrier(0)
#define WAIT_VM0  asm volatile("s_waitcnt vmcnt(0)"  ::: "memory"); \
                  __builtin_amdgcn_sched_barrier(0)
#define WAIT_LGKM asm volatile("s_waitcnt lgkmcnt(0)" ::: "memory"); \
                  __builtin_amdgcn_sched_barrier(0)
#define BAR()     __builtin_amdgcn_s_barrier(); \
                  __builtin_amdgcn_sched_barrier(0)

  // ---- prologue ----
  if (tid < 64) {                            // mask factors (wave0: +1 VMEM)
    int gr = local0 + tid;
    mf_s[tid] = (gr == 0) ? 0.f : mask[b * L_ + gr - 1];
  }
  if (wave == 0) {                           // lambda+carry for step 0
    int cp = sp;                             // t=0 tile pairs 0..31
    float2 lv = lamtab[cp];
    float2 cv = carries[((size_t)(b * SEG_) + s0 + sg) * H_ + cp];
    lrA = lv.x; liA = lv.y; crA = cv.x; ciA = cv.y;
  }
  __builtin_amdgcn_sched_barrier(0);
  stage(0, 0);
  stage(1, 64);
  WAIT_VM9;                                  // retires mf+sc0+stage(0) (w0) /
  BAR();                                     // stage(0) (others); stage(1) flies

  // one K-step; scan uses (lrS,liS,crS,ciS), prefetch lands in (lrN,...)
  auto step = [&](int t, float lrS, float liS, float crS, float ciS,
                  float& lrN, float& liN, float& crN, float& ciN) {
    const int c = t & 1;
    u16* sA = &smem[c][0];
    const u16* sB = &smem[c][4096];

    // ---- scan phase: wave 0 rewrites the A tile in place (BATCHED) ----
    if (wave == 0) {
      char* base = (char*)sA;
      unsigned int vrow[32];
      float frow[32];
#pragma unroll
      for (int i = 0; i < 32; ++i) {         // independent, address-static
        const int row = sg * 32 + i;
        const int addr = row * 128 + (((schunk ^ (row & 7)) & 7) << 4) + soff;
        vrow[i] = *(const unsigned int*)(base + addr);
        frow[i] = mf_s[row];
      }
      float sr = crS, si = ciS;
#pragma unroll
      for (int i = 0; i < 32; ++i) {         // register-only recurrence
        float fac = frow[i];
        float ar = fac * sr, ai = fac * si;
        float nr = b2f((u16)(vrow[i] & 0xffffu)) + lrS * ar - liS * ai;
        float ni = b2f((u16)(vrow[i] >> 16))     + lrS * ai + liS * ar;
        sr = nr; si = ni;
        vrow[i] = (unsigned int)f2b(nr) | ((unsigned int)f2b(ni) << 16);
      }
#pragma unroll
      for (int i = 0; i < 32; ++i) {
        const int row = sg * 32 + i;
        const int addr = row * 128 + (((schunk ^ (row & 7)) & 7) << 4) + soff;
        *(unsigned int*)(base + addr) = vrow[i];
      }
      WAIT_LGKM;                             // scan writes complete
    }
    BAR();                                   // scan visible to all waves

    // ---- fragment reads (A post-scan + B) ----
    bf16x8 af[2][4], bfv[2][4];
#pragma unroll
    for (int kk = 0; kk < 2; ++kk) {
      const int cs = kk * 4 + q;
#pragma unroll
      for (int mt = 0; mt < 4; ++mt) {
        int arow = mt * 16 + r;
        af[kk][mt] = *(const bf16x8*)&sA[(arow * 8 + ksw8(arow, cs)) * 8];
      }
#pragma unroll
      for (int nt = 0; nt < 4; ++nt) {
        int brow = wave * 64 + nt * 16 + r;
        bfv[kk][nt] = *(const bf16x8*)&sB[(brow * 8 + ksw8(brow, cs)) * 8];
      }
    }
    WAIT_LGKM;
    BAR();                                   // all waves done reading buf c

    // ---- prefetch lambda+carry for t+1 (wave0, 2 VMEM) ----
    if (wave == 0 && t < 31) {
      int cp = (t + 1) * 32 + sp;
      float2 lv = lamtab[cp];
      float2 cv = carries[((size_t)(b * SEG_) + s0 + sg) * H_ + cp];
      lrN = lv.x; liN = lv.y; crN = cv.x; ciN = cv.y;
    }
    __builtin_amdgcn_sched_barrier(0);
    if (t < 30) stage(c, (t + 2) * 64);      // overwrite buf c (issue early)
    __builtin_amdgcn_sched_barrier(0);

    // ---- MFMA ----
#pragma unroll
    for (int kk = 0; kk < 2; ++kk)
#pragma unroll
      for (int mt = 0; mt < 4; ++mt)
#pragma unroll
        for (int nt = 0; nt < 4; ++nt)
          acc[mt][nt] = __builtin_amdgcn_mfma_f32_16x16x32_bf16(
              bfv[kk][nt], af[kk][mt], acc[mt][nt], 0, 0, 0);

    // ---- retire stage(t+1) (+wave0's pf(t+1)); keep stage(t+2) in flight ----
    if (t < 30)       { WAIT_VM9; }
    else if (t == 30) { WAIT_VM0; }
    if (t < 31)       { BAR(); }
  };

#pragma unroll 1
  for (int tt = 0; tt < 16; ++tt) {
    step(tt * 2,     lrA, liA, crA, ciA, lrB, liB, crB, ciB);
    step(tt * 2 + 1, lrB, liB, crB, ciB, lrA, liA, crA, ciA);
  }

#undef WAIT_VM9
#undef WAIT_VM0
#undef WAIT_LGKM
#undef BAR

  // ---- epilogue: z = acc + b_out + x; LN over the 512-wide row ----
  float s[4] = {0.f, 0.f, 0.f, 0.f}, ss[4] = {0.f, 0.f, 0.f, 0.f};
#pragma unroll
  for (int mt = 0; mt < 4; ++mt) {
    const size_t grow = (size_t)(m0 + mt * 16 + r);
#pragma unroll
    for (int nt = 0; nt < 4; ++nt) {
      const int c4 = wave * 64 + nt * 16 + q * 4;
      const float4 b4 = *(const float4*)&p0[c4];
      const float4 x4 = *(const float4*)&xg[grow * 512 + c4];
      acc[mt][nt][0] += b4.x + x4.x;
      acc[mt][nt][1] += b4.y + x4.y;
      acc[mt][nt][2] += b4.z + x4.z;
      acc[mt][nt][3] += b4.w + x4.w;
#pragma unroll
      for (int j = 0; j < 4; ++j) {
        float z = acc[mt][nt][j];
        s[mt] += z; ss[mt] += z * z;
      }
    }
  }
#pragma unroll
  for (int mt = 0; mt < 4; ++mt) {           // reduce across q (lanes ^16,^32)
    s[mt]  += __shfl_xor(s[mt], 16);  s[mt]  += __shfl_xor(s[mt], 32);
    ss[mt] += __shfl_xor(ss[mt], 16); ss[mt] += __shfl_xor(ss[mt], 32);
  }
  if (q == 0) {
#pragma unroll
    for (int mt = 0; mt < 4; ++mt) {
      const int lr_ = mt * 16 + r;
      red_s[wave * 64 + lr_]  = s[mt];
      red_ss[wave * 64 + lr_] = ss[mt];
    }
  }
  __syncthreads();
#pragma unroll
  for (int mt = 0; mt < 4; ++mt) {
    const int lr_ = mt * 16 + r;
    float S = 0.f, SS = 0.f;
#pragma unroll
    for (int w = 0; w < 8; ++w) {
      S  += red_s[w * 64 + lr_];
      SS += red_ss[w * 64 + lr_];
    }
    const float mean = S * (1.f / 512.f);
    const float var  = SS * (1.f / 512.f) - mean * mean;
    const float inv  = rsqrtf(var + 1e-5f);
    const size_t grow = (size_t)(m0 + lr_);
#pragma unroll
    for (int nt = 0; nt < 4; ++nt) {
      const int c4 = wave * 64 + nt * 16 + q * 4;
      const float4 w4 = *(const float4*)&lnw[c4];
      const float4 g4 = *(const float4*)&lnb[c4];
      float4 o;
      o.x = (acc[mt][nt][0] - mean) * inv * w4.x + g4.x;
      o.y = (acc[mt][nt][1] - mean) * inv * w4.y + g4.y;
      o.z = (acc[mt][nt][2] - mean) * inv * w4.z + g4.z;
      o.w = (acc[mt][nt][3] - mean) * inv * w4.w + g4.w;
      *(float4*)&out[grow * 512 + c4] = o;
    }
  }
}

// ---------------------------------------------------------------------------
extern "C" void kernel_launch(void* const* d_in, const int* in_sizes, int n_in,
                              void* d_out, int out_size, void* d_ws, size_t ws_size,
                              hipStream_t stream) {
  (void)in_sizes; (void)n_in; (void)out_size; (void)ws_size;
  const float* x      = (const float*)d_in[0];
  const float* mask   = (const float*)d_in[1];
  const float* params = (const float*)d_in[2];   // [3][1024]
  const float* Wire   = (const float*)d_in[3];
  const float* Wiim   = (const float*)d_in[4];
  const float* bire   = (const float*)d_in[5];
  const float* biim   = (const float*)d_in[6];
  const float* Wore   = (const float*)d_in[7];
  const float* Woim   = (const float*)d_in[8];
  const float* bore   = (const float*)d_in[9];
  // d_in[10] = b_out_im: only affects Im(y), discarded by .real
  const float* lnw    = (const float*)d_in[11];
  const float* lnb    = (const float*)d_in[12];

  // Workspace (~105 MB).
  //   [0, 16.7M):        xb (gemm1 input)
  //   [16.7M, 25.2M):    segfin 4M | carries 4M | prodm
  //   [25.2M, 33.5M):    lamtab 8K (at 26214400)
  //   [33.5M, 100.7M):   h (67 MB, pre-scan xh)
  //   [100.7M .. ]:      winb 2M | wcat 2M | bb 8K
  char* ws = (char*)d_ws;
  u16*    xb      = (u16*)   (ws);
  float2* segfin  = (float2*)(ws + (size_t)16777216);
  float2* carries = (float2*)(ws + (size_t)20971520);
  float*  prodm   = (float*) (ws + (size_t)25165824);
  float2* lamtab  = (float2*)(ws + (size_t)26214400);
  u16*    h       = (u16*)   (ws + (size_t)33554432);
  u16*    winb    = (u16*)   (ws + (size_t)100663296);
  u16*    wcat    = (u16*)   (ws + (size_t)102760448);
  float*  bb      = (float*) (ws + (size_t)104857600);

  prep_all<<<2048, 256, 0, stream>>>(x, xb, Wire, Wiim, Wore, Woim,
                                     bire, biim, params, winb, wcat, bb, lamtab);

  // xh = x @ winb^T + bb (pre-scan) + segfin/prodm   (M=16384,N=2048,K=512)
  gemm_scan<<<dim3(128, 16), 256, 0, stream>>>(
      xb, winb, mask, params, h, bb, segfin, prodm);

  scan_carry<<<32, 256, 0, stream>>>(segfin, prodm, params, carries);

  // out = LN( scan(xh) @ wcat^T + b_out_re + x )   (M=16384, N=512, K=2048)
  gemm2_ln<<<256, 512, 0, stream>>>(h, wcat, x, bore, lnw, lnb,
                                    mask, lamtab, carries, (float*)d_out);
}

// Round 10
// 230.520 us; speedup vs baseline: 1.3867x; 1.3867x over previous
//
#include <hip/hip_runtime.h>
#include <hip/hip_bf16.h>
#include <cstdint>
#include <cstddef>

// ---------------------------------------------------------------------------
// LRU layer (fp32 I/O): h = scan( (x W_in^T + b_in)*gamma, lambda, mask )
//                       out = LN( Re(h W_out^T + b_out) + x )
// B=8 L=2048 D=512 H=1024.
// ROUND-19 = ROUND-4 + CONTRACTION-PINNED SCAN ARITHMETIC.  R9 proved the
// absmax is toolchain-dependent: identical source measured 0.078 (R4,
// cached container) vs 0.109 FAIL (R9, fresh container, different hipcc).
// Only FMA-contraction choice is codegen-variable without fast-math, and it
// is amplified through the 2048-step resonant recurrence.  All three scan
// sites (gemm_scan ep3, scan_carry, scan_full) now use fmul_rn(a,b) =
// __builtin_fmaf(a,b,0) -- a single-rounded product that an opaque call
// keeps un-fusable -- arranged in numpy's exact complex-mul form
// (re = ac-bd, im = ad+bc, then add base).  This matches the np reference's
// rounding sequence, making the kernel's absmax deterministic at the
// low end of the observed cluster (~0.07).  No perf change (fma = mul rate).
// Pipeline facts (R8 counters): gemm_scan 44us (780 TF, structure ceiling),
// scan_full 22us (HBM-bound), gemm2_ln 63us (L2->LDS supply-bound),
// prep 17.6us.  gemm2_ln: 64x512 full-LN-row tile, cooperative gl2lds
// double-buffer, counted s_waitcnt vmcnt(9) + raw s_barrier.
// Pipeline: prep_all -> gemm_scan -> scan_carry -> scan_full -> gemm2_ln.
// ---------------------------------------------------------------------------

typedef unsigned short u16;
typedef __attribute__((ext_vector_type(8))) short bf16x8;   // 8 bf16 = 4 VGPRs
typedef __attribute__((ext_vector_type(4))) float f32x4;

#define B_    8
#define L_    2048
#define D_    512
#define H_    1024
#define M_    (B_ * L_)      // 16384 rows
#define SEG_  64             // scan segments per batch
#define T_    (L_ / SEG_)    // 32 steps/segment

__device__ __forceinline__ float b2f(u16 u) {
  union { unsigned int i; float f; } v; v.i = ((unsigned int)u) << 16; return v.f;
}
__device__ __forceinline__ u16 f2b(float f) {
  union { float f; unsigned int i; } v; v.f = f;
  unsigned int x = v.i;
  return (u16)((x + 0x7fffu + ((x >> 16) & 1u)) >> 16);   // RNE
}
// single-rounded product the compiler cannot re-contract into a later add
__device__ __forceinline__ float fmul_rn(float a, float b) {
  return __builtin_fmaf(a, b, 0.0f);
}

// async global->LDS, 16B per lane. LDS dst must be wave-uniform base + lane*16.
__device__ __forceinline__ void gl2lds16(const void* g, void* l) {
  __builtin_amdgcn_global_load_lds(
      (const __attribute__((address_space(1))) void*)g,
      (__attribute__((address_space(3))) void*)l, 16, 0, 0);
}

// XOR swizzle of the 8 16B-chunks in a 64-wide K row (BK=64).
__device__ __forceinline__ int ksw8(int row, int c) {
  return (c ^ (row & 7)) & 7;
}

// ---------------------------------------------------------------------------
// prep_all: x fp32->bf16 + interleaved weight prep:
//   winb[2c][k]   = bf16(W_in_re[c][k] * gamma_c)
//   winb[2c+1][k] = bf16(W_in_im[c][k] * gamma_c)
//   wcat[d][2c]   = bf16(W_out_re[d][c]);  wcat[d][2c+1] = bf16(-W_out_im[d][c])
//   bb[2c] = b_in_re[c]*gamma_c;  bb[2c+1] = b_in_im[c]*gamma_c
// ---------------------------------------------------------------------------
__global__ __launch_bounds__(256) void prep_all(
    const float* __restrict__ x, u16* __restrict__ xb,
    const float* __restrict__ wire, const float* __restrict__ wiim,
    const float* __restrict__ wore, const float* __restrict__ woim,
    const float* __restrict__ bire, const float* __restrict__ biim,
    const float* __restrict__ params,
    u16* __restrict__ winb, u16* __restrict__ wcat, float* __restrict__ bb)
{
  int i = blockIdx.x * 256 + threadIdx.x;        // 0 .. 524287
#pragma unroll
  for (int j = 0; j < 4; ++j) {                  // x: 2097152 float4 groups
    int gi = i + j * 524288;
    float4 v = ((const float4*)x)[gi];
    ushort4 o;
    o.x = f2b(v.x); o.y = f2b(v.y); o.z = f2b(v.z); o.w = f2b(v.w);
    ((ushort4*)xb)[gi] = o;
  }
  {
    int cp = i >> 9, k = i & 511;                // W_in: (pair, k)
    float g = expf(params[2 * H_ + cp]);
    winb[(size_t)(2 * cp) * 512 + k]     = f2b(wire[i] * g);
    winb[(size_t)(2 * cp + 1) * 512 + k] = f2b(wiim[i] * g);
  }
  {
    int d = i >> 10, c = i & 1023;               // W_out: (d, c)
    wcat[(size_t)d * 2048 + 2 * c]     = f2b(wore[i]);
    wcat[(size_t)d * 2048 + 2 * c + 1] = f2b(-woim[i]);
  }
  if (i < 1024) {
    float gb = expf(params[2 * H_ + i]);
    bb[2 * i]     = bire[i] * gb;
    bb[2 * i + 1] = biim[i] * gb;
  }
}

// ---------------------------------------------------------------------------
// gemm_scan: xh = x @ winb^T + bb (pre-scan) AND segfin/prodm of the
// segment-local scan over the in-LDS tile.
// 128x128 tile, BK=64, LDS-DMA staging, operand-swapped MFMA.
// ---------------------------------------------------------------------------
__global__ __launch_bounds__(256, 4) void gemm_scan(
    const u16* __restrict__ A, const u16* __restrict__ Bp,
    const float* __restrict__ mask, const float* __restrict__ params,
    u16* __restrict__ h, const float* __restrict__ bb,
    float2* __restrict__ segfin, float* __restrict__ prodm)
{
  __shared__ __align__(16) u16 sAB[16384];   // 32 KB: sA=[0,8192) sB=[8192,..)
  __shared__ float mf[128];
  const int K = 512;

  const int tid  = threadIdx.x;
  const int lane = tid & 63;
  const int wave = tid >> 6;
  const int wm = wave >> 1, wn = wave & 1;
  const int m0 = blockIdx.x * 128;           // m fast axis (XCD A-share)
  const int n0 = blockIdx.y * 128;
  const int b  = m0 >> 11;
  const int local0 = m0 & (L_ - 1);          // row offset within batch

  f32x4 acc[4][4];
#pragma unroll
  for (int i = 0; i < 4; ++i)
#pragma unroll
    for (int j = 0; j < 4; ++j) { f32x4 z = {0.f, 0.f, 0.f, 0.f}; acc[i][j] = z; }

  const int q = lane >> 4;
  const int r = lane & 15;

  for (int k0 = 0; k0 < K; k0 += 64) {
#pragma unroll
    for (int it = 0; it < 4; ++it) {
      int ci  = it * 256 + tid;
      int row = ci >> 3;
      int kc  = ksw8(row, ci & 7);
      gl2lds16(A  + (size_t)(m0 + row) * K + k0 + kc * 8, &sAB[ci * 8]);
      gl2lds16(Bp + (size_t)(n0 + row) * K + k0 + kc * 8, &sAB[8192 + ci * 8]);
    }
    __syncthreads();
#pragma unroll
    for (int kk = 0; kk < 2; ++kk) {
      const int cs = kk * 4 + q;
      bf16x8 af[4], bfv[4];
#pragma unroll
      for (int mt = 0; mt < 4; ++mt) {
        int arow = wm * 64 + mt * 16 + r;
        af[mt] = *(const bf16x8*)&sAB[(arow * 8 + ksw8(arow, cs)) * 8];
      }
#pragma unroll
      for (int nt = 0; nt < 4; ++nt) {
        int brow = wn * 64 + nt * 16 + r;
        bfv[nt] = *(const bf16x8*)&sAB[8192 + (brow * 8 + ksw8(brow, cs)) * 8];
      }
#pragma unroll
      for (int mt = 0; mt < 4; ++mt)
#pragma unroll
        for (int nt = 0; nt < 4; ++nt)
          acc[mt][nt] = __builtin_amdgcn_mfma_f32_16x16x32_bf16(
              bfv[nt], af[mt], acc[mt][nt], 0, 0, 0);
    }
    __syncthreads();
  }

  // ---- epilogue 1: bf16(acc+bias) -> sH[time 0..127][chan 0..127] ----
  u16* sH = sAB;                               // 128*128 u16 = 32 KB
  if (tid < 128)                               // stage mask factors
    mf[tid] = (local0 + tid == 0) ? 0.f
                                  : mask[b * L_ + local0 + tid - 1];
#pragma unroll
  for (int mt = 0; mt < 4; ++mt) {
    const int trow = wm * 64 + mt * 16 + r;    // time
    const int sw = (trow & 7) << 4;
#pragma unroll
    for (int nt = 0; nt < 4; ++nt) {
      const int nc = wn * 64 + nt * 16 + q * 4;  // channel (4 consecutive)
      const float4 b4 = *(const float4*)&bb[n0 + nc];
      ushort4 o;
      o.x = f2b(acc[mt][nt][0] + b4.x);
      o.y = f2b(acc[mt][nt][1] + b4.y);
      o.z = f2b(acc[mt][nt][2] + b4.z);
      o.w = f2b(acc[mt][nt][3] + b4.w);
      *(ushort4*)&sH[trow * 128 + (nc ^ sw)] = o;
    }
  }
  __syncthreads();

  // ---- epilogue 2: coalesced pre-scan store (issues early) ----
#pragma unroll
  for (int it = 0; it < 8; ++it) {
    int flat = it * 256 + tid;                 // 0..2047 (16B chunks)
    int row  = flat >> 4;
    int c16  = (flat & 15) * 8;
    bf16x8 v = *(const bf16x8*)&sH[row * 128 + (c16 ^ ((row & 7) << 4))];
    *(bf16x8*)&h[(size_t)(m0 + row) * 2048 + n0 + c16] = v;
  }

  // ---- epilogue 3: per-wave segment scan -> segfin/prodm only ----
  {
    const int sIdx = wave;                     // 4 segments per block
    const int cpG  = (n0 >> 1) + lane;         // global complex pair
    float nu = expf(params[cpG]);
    float th = expf(params[H_ + cpG]);
    float mg = expf(-nu);
    float lr = mg * cosf(th), li = mg * sinf(th);
    float sr = 0.f, si = 0.f, pm = 1.f;
    const int rbase = sIdx * 32;
#pragma unroll
    for (int t = 0; t < 32; ++t) {
      int row = rbase + t;
      int pos = row * 128 + ((lane * 2) ^ ((row & 7) << 4));
      ushort2 v = *(const ushort2*)&sH[pos];
      float fac = mf[row];
      pm *= fac;
      float ar = fmul_rn(fac, sr), ai = fmul_rn(fac, si);
      float nr = b2f(v.x) + (fmul_rn(lr, ar) - fmul_rn(li, ai));
      float ni = b2f(v.y) + (fmul_rn(lr, ai) + fmul_rn(li, ar));
      sr = nr; si = ni;
    }
    const int sG = (local0 >> 5) + sIdx;       // global segment in batch
    segfin[(size_t)(b * SEG_ + sG) * H_ + cpG] = make_float2(sr, si);
    if (lane == 0 && n0 == 0) prodm[b * SEG_ + sG] = pm;
  }
}

// ---------------------------------------------------------------------------
// scan_carry: carries[s] = state entering segment s.
// carry_{s+1} = fin_s + prodm_s * lambda^T * carry_s; lambda^T via 5 sq.
// All complex products contraction-pinned (numpy form).
// ---------------------------------------------------------------------------
__global__ __launch_bounds__(256) void scan_carry(
    const float2* __restrict__ segfin, const float* __restrict__ prodm,
    const float* __restrict__ params, float2* __restrict__ carries)
{
  int idx = blockIdx.x * 256 + threadIdx.x;   // 0..8191
  int b = idx >> 10, cp = idx & 1023;
  float nu = expf(params[cp]);
  float th = expf(params[H_ + cp]);
  float mg = expf(-nu);
  float ltr = mg * cosf(th), lti = mg * sinf(th);
#pragma unroll
  for (int sq = 0; sq < 5; ++sq) {            // lambda^(2^5), T=32
    float nr = fmul_rn(ltr, ltr) - fmul_rn(lti, lti);
    float ni = 2.f * fmul_rn(ltr, lti);       // np: ad+bc = 2*round(ltr*lti)
    ltr = nr; lti = ni;
  }
  float cr = 0.f, ci = 0.f;
  float2 fin = segfin[(size_t)(b * SEG_) * H_ + cp];
  float pmv = prodm[b * SEG_];
  for (int s = 0; s < SEG_; ++s) {
    size_t o = (size_t)(b * SEG_ + s) * H_ + cp;
    carries[o] = make_float2(cr, ci);
    float2 finn; float pmn;
    if (s + 1 < SEG_) { finn = segfin[o + H_]; pmn = prodm[b * SEG_ + s + 1]; }
    float tr = fmul_rn(ltr, cr) - fmul_rn(lti, ci);
    float ti = fmul_rn(ltr, ci) + fmul_rn(lti, cr);
    float nr = fin.x + fmul_rn(pmv, tr);
    float ni = fin.y + fmul_rn(pmv, ti);
    cr = nr; ci = ni;
    fin = finn; pmv = pmn;
  }
}

// ---------------------------------------------------------------------------
// scan_full: FULL recurrence per segment, fp32 state seeded from carries;
// h rewritten in place with exactly one bf16 rounding per element.
// Recurrence contraction-pinned (numpy form, same as the other scan sites).
// ---------------------------------------------------------------------------
__global__ __launch_bounds__(256) void scan_full(
    u16* __restrict__ h, const float* __restrict__ mask,
    const float* __restrict__ params, const float2* __restrict__ carries)
{
  const int s = blockIdx.x, b = blockIdx.y;
  const int pa = threadIdx.x * 4;              // first of 4 pairs
  float lr[4], li[4], sr[4], si[4];
#pragma unroll
  for (int j = 0; j < 4; ++j) {
    int cp = pa + j;
    float nu = expf(params[cp]);
    float th = expf(params[H_ + cp]);
    float mg = expf(-nu);
    lr[j] = mg * cosf(th);
    li[j] = mg * sinf(th);
    float2 cv = carries[(size_t)(b * SEG_ + s) * H_ + cp];
    sr[j] = cv.x; si[j] = cv.y;
  }
  const int t0 = s * T_;
  u16* p = h + (size_t)(b * L_ + t0) * 2048 + pa * 2;
  const float* mp = mask + b * L_ + t0;
  float fac0;                                  // block-uniform, no OOB
  if (t0 == 0) fac0 = 0.f; else fac0 = mask[b * L_ + t0 - 1];

  bf16x8 buf[2][8];
#pragma unroll
  for (int j = 0; j < 8; ++j)
    buf[0][j] = *(const bf16x8*)(p + (size_t)j * 2048);
#pragma unroll
  for (int ch = 0; ch < T_ / 8; ++ch) {
    const int cur = ch & 1, nxt = cur ^ 1;
    if (ch < T_ / 8 - 1) {
      u16* pn = p + (size_t)(ch + 1) * 8 * 2048;
#pragma unroll
      for (int j = 0; j < 8; ++j)
        buf[nxt][j] = *(const bf16x8*)(pn + (size_t)j * 2048);
    }
#pragma unroll
    for (int j = 0; j < 8; ++j) {
      int i = ch * 8 + j;
      float fac = (i == 0) ? fac0 : mp[i - 1];
      u16 vv[8], ov[8];
      *(bf16x8*)vv = buf[cur][j];
#pragma unroll
      for (int k = 0; k < 4; ++k) {
        float ar = fmul_rn(fac, sr[k]), ai = fmul_rn(fac, si[k]);
        float nr = b2f(vv[2 * k])
                   + (fmul_rn(lr[k], ar) - fmul_rn(li[k], ai));
        float ni = b2f(vv[2 * k + 1])
                   + (fmul_rn(lr[k], ai) + fmul_rn(li[k], ar));
        sr[k] = nr; si[k] = ni;
        ov[2 * k]     = f2b(nr);
        ov[2 * k + 1] = f2b(ni);
      }
      *(bf16x8*)(p + (size_t)i * 2048) = *(bf16x8*)ov;
    }
  }
}

// ---------------------------------------------------------------------------
// gemm2_ln: out = LN( h @ wcat^T + b_out_re + x ).
// Tile 64(M) x 512(N = full LN row), 512 threads = 8 waves (1m x 8n), per
// wave 64x64 output, acc[4][4].  COOPERATIVE double-buffered LDS staging
// (A 8 KB + B 64 KB per buffer, 144 KB total), m201-style sync:
//   frag ds_reads -> lgkmcnt(0) -> s_barrier          (all waves read buf c)
//   stage(t+2) into buf c (9 gl2lds/wave)             (issue early)
//   32 MFMA                                           (hides DMA)
//   s_waitcnt vmcnt(9) -> s_barrier                   (stage(t+1) landed
//                                                      everywhere; stage(t+2)
//                                                      stays in flight)
// No vmcnt(0) drain in the main loop.  Epilogue: z=acc+bias+x, row mean/var
// via shfl(q) + 8-wave LDS reduce, normalize, fp32 store.
// ---------------------------------------------------------------------------
__global__ __launch_bounds__(512, 2) void gemm2_ln(
    const u16* __restrict__ A, const u16* __restrict__ Bp,
    const float* __restrict__ xg, const float* __restrict__ p0,
    const float* __restrict__ lnw, const float* __restrict__ lnb,
    float* __restrict__ out)
{
  __shared__ __align__(16) u16 smem[2][36864];    // 2 x 72 KB: A[0,4K) B[4K,36K)

  const int K = 2048;
  const int tid  = threadIdx.x;
  const int lane = tid & 63;
  const int wave = tid >> 6;                 // 0..7 == n-block
  const int m0 = blockIdx.x * 64;
  const int q = lane >> 4;
  const int r = lane & 15;

  f32x4 acc[4][4];
#pragma unroll
  for (int i = 0; i < 4; ++i)
#pragma unroll
    for (int j = 0; j < 4; ++j) { f32x4 z = {0.f, 0.f, 0.f, 0.f}; acc[i][j] = z; }

  // stage one BK=64 K-tile into buffer bsel: exactly 9 gl2lds per thread
  // (A: 512 chunks = 1/thread, B: 4096 chunks = 8/thread), uniform per wave.
  auto stage = [&](int bsel, int k0) {
    u16* sA = &smem[bsel][0];
    u16* sB = &smem[bsel][4096];
    {
      int ci  = tid;                         // 64 rows x 8 chunks
      int row = ci >> 3;
      int kc  = ksw8(row, ci & 7);
      gl2lds16(A + (size_t)(m0 + row) * K + k0 + kc * 8, sA + ci * 8);
    }
#pragma unroll
    for (int it = 0; it < 8; ++it) {         // 512 rows x 8 chunks
      int ci  = it * 512 + tid;
      int row = ci >> 3;
      int kc  = ksw8(row, ci & 7);
      gl2lds16(Bp + (size_t)row * K + k0 + kc * 8, sB + ci * 8);
    }
  };

#define WAIT_VM9  asm volatile("s_waitcnt vmcnt(9)"  ::: "memory"); \
                  __builtin_amdgcn_sched_barrier(0)
#define WAIT_VM0  asm volatile("s_waitcnt vmcnt(0)"  ::: "memory"); \
                  __builtin_amdgcn_sched_barrier(0)
#define WAIT_LGKM asm volatile("s_waitcnt lgkmcnt(0)" ::: "memory"); \
                  __builtin_amdgcn_sched_barrier(0)
#define BAR()     __builtin_amdgcn_s_barrier(); \
                  __builtin_amdgcn_sched_barrier(0)

  // prologue: 18 DMAs in flight; vmcnt(9) retires stage(0); barrier makes
  // buf0 globally valid while stage(1) stays in flight.
  stage(0, 0);
  stage(1, 64);
  WAIT_VM9;
  BAR();

  for (int t = 0; t < 32; ++t) {
    const int c = t & 1;
    const u16* sA = &smem[c][0];
    const u16* sB = &smem[c][4096];

    // 1. fragment ds_reads from buf c (16 x ds_read_b128 per lane)
    bf16x8 af[2][4], bfv[2][4];
#pragma unroll
    for (int kk = 0; kk < 2; ++kk) {
      const int cs = kk * 4 + q;
#pragma unroll
      for (int mt = 0; mt < 4; ++mt) {
        int arow = mt * 16 + r;
        af[kk][mt] = *(const bf16x8*)&sA[(arow * 8 + ksw8(arow, cs)) * 8];
      }
#pragma unroll
      for (int nt = 0; nt < 4; ++nt) {
        int brow = wave * 64 + nt * 16 + r;
        bfv[kk][nt] = *(const bf16x8*)&sB[(brow * 8 + ksw8(brow, cs)) * 8];
      }
    }
    WAIT_LGKM;
    BAR();                                   // all waves done reading buf c

    if (t < 30) stage(c, (t + 2) * 64);      // overwrite buf c (issue early)
    __builtin_amdgcn_sched_barrier(0);

    // 2. MFMA on registers (DMA latency hides under this)
#pragma unroll
    for (int kk = 0; kk < 2; ++kk)
#pragma unroll
      for (int mt = 0; mt < 4; ++mt)
#pragma unroll
        for (int nt = 0; nt < 4; ++nt)
          acc[mt][nt] = __builtin_amdgcn_mfma_f32_16x16x32_bf16(
              bfv[kk][nt], af[kk][mt], acc[mt][nt], 0, 0, 0);

    // 3. retire stage(t+1) only; stage(t+2) stays in flight across barrier
    if (t < 30)      { WAIT_VM9; }
    else if (t == 30){ WAIT_VM0; }
    if (t < 31)      { BAR(); }
  }

#undef WAIT_VM9
#undef WAIT_VM0
#undef WAIT_LGKM
#undef BAR

  // ---- epilogue: z = acc + b_out + x; LN over the 512-wide row ----
  __syncthreads();                           // all waves done with smem
  float* red_s  = (float*)&smem[0][0];       // [8][64]
  float* red_ss = red_s + 512;               // [8][64]

  float s[4] = {0.f, 0.f, 0.f, 0.f}, ss[4] = {0.f, 0.f, 0.f, 0.f};
#pragma unroll
  for (int mt = 0; mt < 4; ++mt) {
    const size_t grow = (size_t)(m0 + mt * 16 + r);
#pragma unroll
    for (int nt = 0; nt < 4; ++nt) {
      const int c4 = wave * 64 + nt * 16 + q * 4;
      const float4 b4 = *(const float4*)&p0[c4];
      const float4 x4 = *(const float4*)&xg[grow * 512 + c4];
      acc[mt][nt][0] += b4.x + x4.x;
      acc[mt][nt][1] += b4.y + x4.y;
      acc[mt][nt][2] += b4.z + x4.z;
      acc[mt][nt][3] += b4.w + x4.w;
#pragma unroll
      for (int j = 0; j < 4; ++j) {
        float z = acc[mt][nt][j];
        s[mt] += z; ss[mt] += z * z;
      }
    }
  }
#pragma unroll
  for (int mt = 0; mt < 4; ++mt) {           // reduce across q (lanes ^16,^32)
    s[mt]  += __shfl_xor(s[mt], 16);  s[mt]  += __shfl_xor(s[mt], 32);
    ss[mt] += __shfl_xor(ss[mt], 16); ss[mt] += __shfl_xor(ss[mt], 32);
  }
  if (q == 0) {
#pragma unroll
    for (int mt = 0; mt < 4; ++mt) {
      const int lr_ = mt * 16 + r;
      red_s[wave * 64 + lr_]  = s[mt];
      red_ss[wave * 64 + lr_] = ss[mt];
    }
  }
  __syncthreads();
#pragma unroll
  for (int mt = 0; mt < 4; ++mt) {
    const int lr_ = mt * 16 + r;
    float S = 0.f, SS = 0.f;
#pragma unroll
    for (int w = 0; w < 8; ++w) {
      S  += red_s[w * 64 + lr_];
      SS += red_ss[w * 64 + lr_];
    }
    const float mean = S * (1.f / 512.f);
    const float var  = SS * (1.f / 512.f) - mean * mean;
    const float inv  = rsqrtf(var + 1e-5f);
    const size_t grow = (size_t)(m0 + lr_);
#pragma unroll
    for (int nt = 0; nt < 4; ++nt) {
      const int c4 = wave * 64 + nt * 16 + q * 4;
      const float4 w4 = *(const float4*)&lnw[c4];
      const float4 g4 = *(const float4*)&lnb[c4];
      float4 o;
      o.x = (acc[mt][nt][0] - mean) * inv * w4.x + g4.x;
      o.y = (acc[mt][nt][1] - mean) * inv * w4.y + g4.y;
      o.z = (acc[mt][nt][2] - mean) * inv * w4.z + g4.z;
      o.w = (acc[mt][nt][3] - mean) * inv * w4.w + g4.w;
      *(float4*)&out[grow * 512 + c4] = o;
    }
  }
}

// ---------------------------------------------------------------------------
extern "C" void kernel_launch(void* const* d_in, const int* in_sizes, int n_in,
                              void* d_out, int out_size, void* d_ws, size_t ws_size,
                              hipStream_t stream) {
  (void)in_sizes; (void)n_in; (void)out_size; (void)ws_size;
  const float* x      = (const float*)d_in[0];
  const float* mask   = (const float*)d_in[1];
  const float* params = (const float*)d_in[2];   // [3][1024]
  const float* Wire   = (const float*)d_in[3];
  const float* Wiim   = (const float*)d_in[4];
  const float* bire   = (const float*)d_in[5];
  const float* biim   = (const float*)d_in[6];
  const float* Wore   = (const float*)d_in[7];
  const float* Woim   = (const float*)d_in[8];
  const float* bore   = (const float*)d_in[9];
  // d_in[10] = b_out_im: only affects Im(y), discarded by .real
  const float* lnw    = (const float*)d_in[11];
  const float* lnb    = (const float*)d_in[12];

  // Workspace (~105 MB).
  //   [0, 16.7M):        xb (gemm1 input)
  //   [16.7M, 25.2M):    segfin 4M | carries 4M | prodm
  //   [33.5M, 100.7M):   h (67 MB)
  //   [100.7M .. ]:      winb 2M | wcat 2M | bb 8K
  char* ws = (char*)d_ws;
  u16*    xb      = (u16*)   (ws);
  float2* segfin  = (float2*)(ws + (size_t)16777216);
  float2* carries = (float2*)(ws + (size_t)20971520);
  float*  prodm   = (float*) (ws + (size_t)25165824);
  u16*    h       = (u16*)   (ws + (size_t)33554432);
  u16*    winb    = (u16*)   (ws + (size_t)100663296);
  u16*    wcat    = (u16*)   (ws + (size_t)102760448);
  float*  bb      = (float*) (ws + (size_t)104857600);

  prep_all<<<2048, 256, 0, stream>>>(x, xb, Wire, Wiim, Wore, Woim,
                                     bire, biim, params, winb, wcat, bb);

  // xh = x @ winb^T + bb (pre-scan) + segfin/prodm   (M=16384,N=2048,K=512)
  gemm_scan<<<dim3(128, 16), 256, 0, stream>>>(
      xb, winb, mask, params, h, bb, segfin, prodm);

  scan_carry<<<32, 256, 0, stream>>>(segfin, prodm, params, carries);
  scan_full<<<dim3(SEG_, B_), 256, 0, stream>>>(h, mask, params, carries);

  // out = LN( h @ wcat^T + b_out_re + x )   (M=16384, N=512, K=2048)
  gemm2_ln<<<256, 512, 0, stream>>>(h, wcat, x, bore, lnw, lnb, (float*)d_out);
}